// Round 9
// baseline (300.722 us; speedup 1.0000x reference)
//
#include <hip/hip_runtime.h>
#include <hip/hip_bf16.h>

#define B_    4
#define C_    128
#define HW_   16384
#define K_    1024
// softmax runs in log2 domain: fold 128^-0.5 * log2(e) into the QK epilogue FMA
#define SC2_  0.12751734f
#define NEGL_ (-1.4427e7f)        // NEG * log2(e)
#define DTHR_ 8.0f                // defer-max threshold (log2 units): p <= 2^8

using bf16 = __hip_bfloat16;
typedef __bf16 b8v __attribute__((ext_vector_type(8)));
typedef __bf16 b4v __attribute__((ext_vector_type(4)));
typedef __bf16 b2v __attribute__((ext_vector_type(2)));
typedef float  f4v __attribute__((ext_vector_type(4)));

__device__ __forceinline__ b8v ldb8(const void* p) { return *(const b8v*)p; }
__device__ __forceinline__ b4v ldb4(const void* p) { return *(const b4v*)p; }

#define XSTRIDE 272   // 256 B row + 16 pad (b128 frag reads at bank floor)
#define KSTRIDE 272
#define VSTRIDE 136   // proven V layout: 128 B row + 8 pad, ldb4-pair reads

// weight row (f32) -> bf16 fragment with BN scale folded, inline
__device__ __forceinline__ b8v ldw8(const float* wp, float sc) {
    const float4 a = *(const float4*)wp;
    const float4 c = *(const float4*)(wp + 4);
    b8v r;
    r[0] = (__bf16)(a.x * sc); r[1] = (__bf16)(a.y * sc);
    r[2] = (__bf16)(a.z * sc); r[3] = (__bf16)(a.w * sc);
    r[4] = (__bf16)(c.x * sc); r[5] = (__bf16)(c.y * sc);
    r[6] = (__bf16)(c.z * sc); r[7] = (__bf16)(c.w * sc);
    return r;
}

// ---------------------------------------------------------------------------
// prep: EXACT R7 (proven, parallel kv).
//   blk [0,64)       : K projection tile (b = blk>>4, p0 = (blk&15)*64)
//   blk [64,128)     : V projection tile
//   blk [128,1152)   : query transpose (R3-proven f32-staged pattern)
//   blk [1152,1600)  : mega weight prep (Wq1,Wq2,Wo,Wb)
// ---------------------------------------------------------------------------
__global__ __launch_bounds__(256, 4) void prep_kernel(
    const float* __restrict__ query, const float* __restrict__ key, const float* __restrict__ val,
    const float* __restrict__ Wq1, const float* __restrict__ sq1,
    const float* __restrict__ Wq2, const float* __restrict__ sq2,
    const float* __restrict__ Wo,  const float* __restrict__ so,
    const float* __restrict__ Wb,  const float* __restrict__ sb,
    const float* __restrict__ Wk1, const float* __restrict__ sk1, const float* __restrict__ bk1,
    const float* __restrict__ Wk2, const float* __restrict__ sk2, const float* __restrict__ bk2,
    const float* __restrict__ Wv,  const float* __restrict__ sv_, const float* __restrict__ bv,
    bf16* __restrict__ qt, bf16* __restrict__ kbuf, bf16* __restrict__ vbuf,
    __bf16* __restrict__ Wq1p, __bf16* __restrict__ Wq2p,
    __bf16* __restrict__ Wop,  __bf16* __restrict__ Wbp)
{
    __shared__ __align__(16) char SM[34816];
    const int blk = blockIdx.x, t = threadIdx.x;
    const int pl64 = t & 63, cg = t >> 6;

    auto scatter_tp = [&](const float* src, int L, int p0, int b, char* dst) {
#pragma unroll 4
        for (int i2 = 0; i2 < 32; ++i2) {
            const int c = cg * 32 + i2;
            const float f = src[(size_t)(b * 128 + c) * L + p0 + pl64];
            *(__bf16*)(dst + pl64 * XSTRIDE + 2 * c) = (__bf16)f;
        }
    };

    if (blk < 64) {
        // ================= K projection: one 64-position tile =================
        const int b = blk >> 4, p0 = (blk & 15) * 64;
        const int w = t >> 6, lane = t & 63;
        const int pl = lane & 15, quad = lane >> 4;
        const int ob = 32 * w;
        char* Xs = SM;
        char* Ys = SM + 17408;

        b8v W1f[2][4], W2f[2][4];
#pragma unroll
        for (int mt = 0; mt < 2; ++mt)
#pragma unroll
            for (int s = 0; s < 4; ++s) {
                const int row = ob + mt * 16 + pl;
                W1f[mt][s] = ldw8(Wk1 + row * 128 + s * 32 + quad * 8, sk1[row]);
                W2f[mt][s] = ldw8(Wk2 + row * 128 + s * 32 + quad * 8, sk2[row]);
            }

        scatter_tp(key, K_, p0, b, Xs);
        __syncthreads();

        f4v acc[2][4];
#pragma unroll
        for (int mt = 0; mt < 2; ++mt)
#pragma unroll
            for (int nt = 0; nt < 4; ++nt) acc[mt][nt] = (f4v){0.f, 0.f, 0.f, 0.f};
#pragma unroll
        for (int s = 0; s < 4; ++s) {
            b8v Bf[4];
#pragma unroll
            for (int nt = 0; nt < 4; ++nt)
                Bf[nt] = ldb8(Xs + (nt * 16 + pl) * XSTRIDE + s * 64 + quad * 16);
#pragma unroll
            for (int mt = 0; mt < 2; ++mt)
#pragma unroll
                for (int nt = 0; nt < 4; ++nt)
                    acc[mt][nt] = __builtin_amdgcn_mfma_f32_16x16x32_bf16(W1f[mt][s], Bf[nt], acc[mt][nt], 0, 0, 0);
        }
#pragma unroll
        for (int mt = 0; mt < 2; ++mt) {
            const float4 s4 = *(const float4*)(bk1 + ob + mt * 16 + quad * 4);
            const float shf[4] = {s4.x, s4.y, s4.z, s4.w};
#pragma unroll
            for (int nt = 0; nt < 4; ++nt) {
                b4v y;
#pragma unroll
                for (int r = 0; r < 4; ++r) y[r] = (__bf16)fmaxf(acc[mt][nt][r] + shf[r], 0.f);
                *(b4v*)(Ys + (nt * 16 + pl) * XSTRIDE + (ob + mt * 16 + quad * 4) * 2) = y;
            }
        }
        __syncthreads();

        f4v acc2[2][4];
#pragma unroll
        for (int mt = 0; mt < 2; ++mt)
#pragma unroll
            for (int nt = 0; nt < 4; ++nt) acc2[mt][nt] = (f4v){0.f, 0.f, 0.f, 0.f};
#pragma unroll
        for (int s = 0; s < 4; ++s) {
            b8v Bf[4];
#pragma unroll
            for (int nt = 0; nt < 4; ++nt)
                Bf[nt] = ldb8(Ys + (nt * 16 + pl) * XSTRIDE + s * 64 + quad * 16);
#pragma unroll
            for (int mt = 0; mt < 2; ++mt)
#pragma unroll
                for (int nt = 0; nt < 4; ++nt)
                    acc2[mt][nt] = __builtin_amdgcn_mfma_f32_16x16x32_bf16(W2f[mt][s], Bf[nt], acc2[mt][nt], 0, 0, 0);
        }
        bf16* kdst = kbuf + ((size_t)b * K_ + p0) * 128;
#pragma unroll
        for (int mt = 0; mt < 2; ++mt) {
            const float4 s4 = *(const float4*)(bk2 + ob + mt * 16 + quad * 4);
            const float shf[4] = {s4.x, s4.y, s4.z, s4.w};
#pragma unroll
            for (int nt = 0; nt < 4; ++nt) {
                b4v y;
#pragma unroll
                for (int r = 0; r < 4; ++r) y[r] = (__bf16)fmaxf(acc2[mt][nt][r] + shf[r], 0.f);
                *(b4v*)(kdst + (size_t)(nt * 16 + pl) * 128 + ob + mt * 16 + quad * 4) = y;
            }
        }
    } else if (blk < 128) {
        // ================= V projection: one 64-position tile =================
        const int i = blk - 64;
        const int b = i >> 4, p0 = (i & 15) * 64;
        const int w = t >> 6, lane = t & 63;
        const int pl = lane & 15, quad = lane >> 4;
        const int ob = 32 * w;
        char* Xs = SM;

        b8v Wvf[2][4];
#pragma unroll
        for (int mt = 0; mt < 2; ++mt)
#pragma unroll
            for (int s = 0; s < 4; ++s) {
                const int row = ob + mt * 16 + pl;
                Wvf[mt][s] = ldw8(Wv + row * 128 + s * 32 + quad * 8, sv_[row]);
            }

        scatter_tp(val, K_, p0, b, Xs);
        __syncthreads();

        f4v acc[2][4];
#pragma unroll
        for (int mt = 0; mt < 2; ++mt)
#pragma unroll
            for (int nt = 0; nt < 4; ++nt) acc[mt][nt] = (f4v){0.f, 0.f, 0.f, 0.f};
#pragma unroll
        for (int s = 0; s < 4; ++s) {
            b8v Bf[4];
#pragma unroll
            for (int nt = 0; nt < 4; ++nt)
                Bf[nt] = ldb8(Xs + (nt * 16 + pl) * XSTRIDE + s * 64 + quad * 16);
#pragma unroll
            for (int mt = 0; mt < 2; ++mt)
#pragma unroll
                for (int nt = 0; nt < 4; ++nt)
                    acc[mt][nt] = __builtin_amdgcn_mfma_f32_16x16x32_bf16(Wvf[mt][s], Bf[nt], acc[mt][nt], 0, 0, 0);
        }
        bf16* vdst = vbuf + (size_t)b * 128 * K_;
#pragma unroll
        for (int mt = 0; mt < 2; ++mt) {
            const float4 s4 = *(const float4*)(bv + ob + mt * 16 + quad * 4);
            const float shf[4] = {s4.x, s4.y, s4.z, s4.w};
#pragma unroll
            for (int nt = 0; nt < 4; ++nt)
#pragma unroll
                for (int r = 0; r < 4; ++r)
                    vdst[(size_t)(ob + mt * 16 + quad * 4 + r) * K_ + p0 + nt * 16 + pl]
                        = __float2bfloat16(fmaxf(acc[mt][nt][r] + shf[r], 0.f));
        }
    } else if (blk < 1152) {
        // ================= query transpose (R3-proven) =================
        float* Xs2 = (float*)SM;               // f32 [64][129] = 33024 B
        const int i = blk - 128;
        const int b = i >> 8, p0 = (i & 255) * 64;
        const int pl = t & 63, cgq = t >> 6;
#pragma unroll 4
        for (int i2 = 0; i2 < 32; ++i2) {
            const int c = cgq * 32 + i2;
            Xs2[pl * 129 + c] = query[(size_t)(b * 128 + c) * HW_ + p0 + pl];
        }
        __syncthreads();
#pragma unroll 4
        for (int it = 0; it < 16; ++it) {
            const int p = it * 4 + cgq;
            b2v pk2;
            pk2[0] = (__bf16)Xs2[p * 129 + 2 * pl];
            pk2[1] = (__bf16)Xs2[p * 129 + 2 * pl + 1];
            *(b2v*)(qt + ((size_t)b * HW_ + p0 + p) * 128 + 2 * pl) = pk2;
        }
    } else {
        // ================= mega weight prep =================
        const int idx = (blk - 1152) * 256 + t;
        if (idx < 16384)      { Wq1p[idx] = (__bf16)(Wq1[idx] * sq1[idx >> 7]); }
        else if (idx < 32768) { const int i2 = idx - 16384; Wq2p[i2] = (__bf16)(Wq2[i2] * sq2[i2 >> 7]); }
        else if (idx < 49152) { const int i2 = idx - 32768; Wop[i2]  = (__bf16)(Wo[i2]  * so[i2 >> 7]); }
        else                  { const int i2 = idx - 49152; Wbp[i2]  = (__bf16)(Wb[i2]  * sb[i2 >> 8]); }
    }
}

// ---------------------------------------------------------------------------
// mega: R8 with ONE structural change — GEMM1's K-fragments load DIRECTLY
// from global kbuf (L1/L2-hot: all 16 waves/CU read the same 16KB chunk),
// removing K staging + K LDS reads from the saturated LDS pipe. V keeps the
// R8 double-buffer (1 lgkm-barrier/chunk). Attention LDS regions shrink to
// bias + 2 V-tiles. Phases 1/3 and all layouts unchanged (proven R3 code).
// LDS 69632 (phases), 2 blocks/CU. grid (HW/128, B), 512 threads.
// ---------------------------------------------------------------------------
__global__ __launch_bounds__(512, 4) void mega_kernel(
    const bf16* __restrict__ qt, const bf16* __restrict__ kbuf, const bf16* __restrict__ vbuf,
    const int* __restrict__ mask,
    const __bf16* __restrict__ Wq1p, const float* __restrict__ bq1,
    const __bf16* __restrict__ Wq2p, const float* __restrict__ bq2,
    const __bf16* __restrict__ Wop,  const float* __restrict__ bo,
    const __bf16* __restrict__ Wbp,  const float* __restrict__ bb,
    float* __restrict__ out)
{
    __shared__ __align__(16) char S[69632];

    const int t = threadIdx.x, w = t >> 6, lane = t & 63;
    const int pl = lane & 15, quad = lane >> 4;
    const int n0 = blockIdx.x * 128;
    const int b  = blockIdx.y;
    const int ob = 16 * w;                     // 16-channel slice per wave

    char*   RA  = S;
    __bf16* RAh = (__bf16*)S;
    __bf16* RBh = (__bf16*)(S + 34816);
    char* xl = RA + (t >> 4) * XSTRIDE + (t & 15) * 16;

    // ================= phase 1: q projection (into LDS) =================
    {
        const char* qg = (const char*)(qt + ((size_t)b * HW_ + n0) * 128) + t * 16;
#pragma unroll
        for (int i = 0; i < 4; ++i)
            *(float4*)(xl + i * 32 * XSTRIDE) = *(const float4*)(qg + i * 8192);
    }
    {
        b8v W1f[4], W2f[4];
#pragma unroll
        for (int s = 0; s < 4; ++s) {
            W1f[s] = ldb8(Wq1p + (ob + pl) * 128 + s * 32 + quad * 8);
            W2f[s] = ldb8(Wq2p + (ob + pl) * 128 + s * 32 + quad * 8);
        }
        __syncthreads();                       // sync1: q-tile in RA

        f4v a1[8];
#pragma unroll
        for (int nt = 0; nt < 8; ++nt) a1[nt] = (f4v){0.f, 0.f, 0.f, 0.f};
#pragma unroll
        for (int s = 0; s < 4; ++s) {
            b8v Bf[8];
#pragma unroll
            for (int nt = 0; nt < 8; ++nt)
                Bf[nt] = ldb8(RA + (nt * 16 + pl) * XSTRIDE + s * 64 + quad * 16);
#pragma unroll
            for (int nt = 0; nt < 8; ++nt)
                a1[nt] = __builtin_amdgcn_mfma_f32_16x16x32_bf16(W1f[s], Bf[nt], a1[nt], 0, 0, 0);
        }
        {
            const float4 s4 = *(const float4*)(bq1 + ob + quad * 4);
            const float shf[4] = {s4.x, s4.y, s4.z, s4.w};
#pragma unroll
            for (int nt = 0; nt < 8; ++nt) {
                b4v y;
#pragma unroll
                for (int r = 0; r < 4; ++r) y[r] = (__bf16)fmaxf(a1[nt][r] + shf[r], 0.f);
                *(b4v*)&RBh[(nt * 16 + pl) * 136 + ob + quad * 4] = y;
            }
        }
        __syncthreads();                       // sync2: y1 in RB, RA reads done

        f4v a2[8];
#pragma unroll
        for (int nt = 0; nt < 8; ++nt) a2[nt] = (f4v){0.f, 0.f, 0.f, 0.f};
#pragma unroll
        for (int s = 0; s < 4; ++s) {
            b8v Bf[8];
#pragma unroll
            for (int nt = 0; nt < 8; ++nt)
                Bf[nt] = *(const b8v*)&RBh[(nt * 16 + pl) * 136 + s * 32 + quad * 8];
#pragma unroll
            for (int nt = 0; nt < 8; ++nt)
                a2[nt] = __builtin_amdgcn_mfma_f32_16x16x32_bf16(W2f[s], Bf[nt], a2[nt], 0, 0, 0);
        }
        {
            const float4 s4 = *(const float4*)(bq2 + ob + quad * 4);
            const float shf[4] = {s4.x, s4.y, s4.z, s4.w};
#pragma unroll
            for (int nt = 0; nt < 8; ++nt) {
                b4v y;
#pragma unroll
                for (int r = 0; r < 4; ++r) y[r] = (__bf16)fmaxf(a2[nt][r] + shf[r], 0.f);
                *(b4v*)&RAh[(nt * 16 + pl) * 136 + ob + quad * 4] = y;
            }
        }
        __syncthreads();                       // sync3: q[pos][c] in RA
    }

    // q fragments: wave w owns queries w*16..w*16+15 (1 tile)
    b8v qf[4];
#pragma unroll
    for (int s = 0; s < 4; ++s)
        qf[s] = ldb8(RA + (w * 16 + pl) * XSTRIDE + s * 64 + quad * 16);
    __syncthreads();                           // sync4: qf read, RA free

    // ================= phase 2: attention =================
    // LDS: bias 4096 | vt0 17408 | vt1 17408  (K is NOT staged — global reads)
    float* bias = (float*)S;
    char* vt0 = S + 4096;
    char* vt1 = S + 21504;

    const bf16* kpt = kbuf + (size_t)b * K_ * 128;
    const bf16* vpt = vbuf + (size_t)b * 128 * K_;
    const char* vg = (const char*)(vpt + (size_t)(t >> 3) * K_) + (t & 7) * 16;
    const int vlo = (t >> 3) * VSTRIDE + (t & 7) * 16;

    float4 v_r0 = *(const float4*)(vg);
    float4 v_r1 = *(const float4*)(vg + 131072);

    for (int i2 = t; i2 < K_; i2 += 512)
        bias[i2] = (mask[b * K_ + i2] != 0) ? 0.f : NEGL_;

    {   // prologue: stage chunk 0 into vt0
        char* vlp = vt0 + vlo;
        *(float4*)(vlp)                = v_r0;
        *(float4*)(vlp + 64 * VSTRIDE) = v_r1;
    }

    f4v ac[8];
#pragma unroll
    for (int i = 0; i < 8; ++i) ac[i] = (f4v){0.f, 0.f, 0.f, 0.f};
    float mrun = -3.0e38f, lrun = 0.f;

    // lgkm-only barrier: LDS ops drained, global loads stay in flight.
#define RAW_BARRIER()                                                 \
    __builtin_amdgcn_sched_barrier(0);                                \
    asm volatile("s_waitcnt lgkmcnt(0)" ::: "memory");                \
    __builtin_amdgcn_s_barrier();                                     \
    __builtin_amdgcn_sched_barrier(0);

    RAW_BARRIER()                              // vt0 + bias visible

    for (int chunk = 0; chunk < 16; ++chunk) {
        const char* vtc = (chunk & 1) ? vt1 : vt0;
        char* vtn = (chunk & 1) ? vt0 : vt1;
        const int k0 = chunk * 64;

        // issue next chunk's V loads now; staged after GEMM1/softmax
        if (chunk < 15) {
            const char* vgn = vg + (chunk + 1) * 128;
            v_r0 = *(const float4*)(vgn);
            v_r1 = *(const float4*)(vgn + 131072);
        }

        // ---- GEMM1: K-fragments DIRECT FROM GLOBAL (L1/L2-hot kbuf)
        f4v sv[4];
        __builtin_amdgcn_s_setprio(1);
#pragma unroll
        for (int kt = 0; kt < 4; ++kt) {
            f4v a = (f4v){0.f, 0.f, 0.f, 0.f};
            const char* krow = (const char*)kpt + (size_t)(k0 + kt * 16 + pl) * 256 + quad * 16;
#pragma unroll
            for (int s = 0; s < 4; ++s)
                a = __builtin_amdgcn_mfma_f32_16x16x32_bf16(ldb8(krow + s * 64), qf[s], a, 0, 0, 0);
            const float4 b4 = *(const float4*)&bias[k0 + kt * 16 + quad * 4];
            const float bb4[4] = {b4.x, b4.y, b4.z, b4.w};
#pragma unroll
            for (int r = 0; r < 4; ++r) sv[kt][r] = a[r] * SC2_ + bb4[r];
        }
        __builtin_amdgcn_s_setprio(0);

        // ---- online softmax (deferred rescale, T13)
        float ml = sv[0][0];
#pragma unroll
        for (int kt = 0; kt < 4; ++kt)
#pragma unroll
            for (int r = 0; r < 4; ++r) ml = fmaxf(ml, sv[kt][r]);
        ml = fmaxf(ml, __shfl_xor(ml, 16, 64));
        ml = fmaxf(ml, __shfl_xor(ml, 32, 64));

        if (__any(ml > mrun + DTHR_)) {
            const float mn = fmaxf(mrun, ml);
            const float al = exp2f(mrun - mn);
            lrun *= al; mrun = mn;
            float ar[4];
#pragma unroll
            for (int r = 0; r < 4; ++r) ar[r] = __shfl(al, quad * 4 + r, 64);
#pragma unroll
            for (int ct = 0; ct < 8; ++ct)
#pragma unroll
                for (int r = 0; r < 4; ++r) ac[ct][r] *= ar[r];
        }

        b4v pk[4];
        float rs = 0.f;
#pragma unroll
        for (int kt = 0; kt < 4; ++kt)
#pragma unroll
            for (int r = 0; r < 4; ++r) {
                const float p = exp2f(sv[kt][r] - mrun); rs += p; pk[kt][r] = (__bf16)p;
            }
        rs += __shfl_xor(rs, 16, 64); rs += __shfl_xor(rs, 32, 64);
        lrun += rs;

        // ---- stage next V chunk into the other buffer (disjoint from reads)
        if (chunk < 15) {
            char* vlp = vtn + vlo;
            *(float4*)(vlp)                = v_r0;
            *(float4*)(vlp + 64 * VSTRIDE) = v_r1;
        }

        // ---- GEMM2 (V from LDS, current buffer)
        const b8v A0 = __builtin_shufflevector(pk[0], pk[1], 0, 1, 2, 3, 4, 5, 6, 7);
        const b8v A1 = __builtin_shufflevector(pk[2], pk[3], 0, 1, 2, 3, 4, 5, 6, 7);
        __builtin_amdgcn_s_setprio(1);
#pragma unroll
        for (int ct = 0; ct < 8; ++ct) {
            const char* vrow = vtc + (ct * 16 + pl) * VSTRIDE + quad * 8;
            const b8v B0 = __builtin_shufflevector(ldb4(vrow),      ldb4(vrow + 32), 0, 1, 2, 3, 4, 5, 6, 7);
            const b8v B1 = __builtin_shufflevector(ldb4(vrow + 64), ldb4(vrow + 96), 0, 1, 2, 3, 4, 5, 6, 7);
            ac[ct] = __builtin_amdgcn_mfma_f32_16x16x32_bf16(A0, B0, ac[ct], 0, 0, 0);
            ac[ct] = __builtin_amdgcn_mfma_f32_16x16x32_bf16(A1, B1, ac[ct], 0, 0, 0);
        }
        __builtin_amdgcn_s_setprio(0);

        RAW_BARRIER()                          // V reads+writes drained; swap
    }
#undef RAW_BARRIER

    // ---- epilogue: normalized ctx -> RA [pos][c] bf16
    {
        float inv[4];
#pragma unroll
        for (int r = 0; r < 4; ++r) inv[r] = 1.f / __shfl(lrun, quad * 4 + r, 64);
#pragma unroll
        for (int ct = 0; ct < 8; ++ct)
#pragma unroll
            for (int r = 0; r < 4; ++r)
                RAh[(w * 16 + quad * 4 + r) * 136 + ct * 16 + pl] = (__bf16)(ac[ct][r] * inv[r]);
    }
    __syncthreads();                           // sync5: ctx in RA

    // ================= phase 3: final =================
    b8v Wof[4];
#pragma unroll
    for (int s = 0; s < 4; ++s)
        Wof[s] = ldb8(Wop + (ob + pl) * 128 + s * 32 + quad * 8);

    const char* qg2 = (const char*)(qt + ((size_t)b * HW_ + n0) * 128) + t * 16;
    float4 q_s0 = *(const float4*)(qg2);
    float4 q_s1 = *(const float4*)(qg2 + 8192);
    float4 q_s2 = *(const float4*)(qg2 + 16384);
    float4 q_s3 = *(const float4*)(qg2 + 24576);

    {
        f4v f1[8];
#pragma unroll
        for (int nt = 0; nt < 8; ++nt) f1[nt] = (f4v){0.f, 0.f, 0.f, 0.f};
#pragma unroll
        for (int s = 0; s < 4; ++s) {
            b8v Bf[8];
#pragma unroll
            for (int nt = 0; nt < 8; ++nt)
                Bf[nt] = ldb8(RA + (nt * 16 + pl) * XSTRIDE + s * 64 + quad * 16);
#pragma unroll
            for (int nt = 0; nt < 8; ++nt)
                f1[nt] = __builtin_amdgcn_mfma_f32_16x16x32_bf16(Wof[s], Bf[nt], f1[nt], 0, 0, 0);
        }
        {
            const float4 s4 = *(const float4*)(bo + ob + quad * 4);
            const float shf[4] = {s4.x, s4.y, s4.z, s4.w};
#pragma unroll
            for (int nt = 0; nt < 8; ++nt) {
                b4v y;
#pragma unroll
                for (int r = 0; r < 4; ++r) y[r] = (__bf16)fmaxf(f1[nt][r] + shf[r], 0.f);
                *(b4v*)&RBh[(nt * 16 + pl) * 136 + ob + quad * 4] = y;
            }
        }
    }
    __syncthreads();                           // sync6: ctx2 in RB, RA reads done

    *(float4*)(xl)                 = q_s0;
    *(float4*)(xl + 32 * XSTRIDE)  = q_s1;
    *(float4*)(xl + 64 * XSTRIDE)  = q_s2;
    *(float4*)(xl + 96 * XSTRIDE)  = q_s3;
    __syncthreads();                           // sync7: qt in RA

    {
        f4v f2[2][8];
#pragma unroll
        for (int mt = 0; mt < 2; ++mt)
#pragma unroll
            for (int nt = 0; nt < 8; ++nt) f2[mt][nt] = (f4v){0.f, 0.f, 0.f, 0.f};
#pragma unroll
        for (int ks = 0; ks < 8; ++ks) {
            b8v Af[2];
#pragma unroll
            for (int mt = 0; mt < 2; ++mt)
                Af[mt] = ldb8(Wbp + (size_t)(32 * w + mt * 16 + pl) * 256 + ks * 32 + quad * 8);
            b8v Bf[8];
            if (ks < 4) {
#pragma unroll
                for (int nt = 0; nt < 8; ++nt)
                    Bf[nt] = *(const b8v*)&RBh[(nt * 16 + pl) * 136 + ks * 32 + quad * 8];
            } else {
#pragma unroll
                for (int nt = 0; nt < 8; ++nt)
                    Bf[nt] = ldb8(RA + (nt * 16 + pl) * XSTRIDE + (ks - 4) * 64 + quad * 16);
            }
#pragma unroll
            for (int mt = 0; mt < 2; ++mt)
#pragma unroll
                for (int nt = 0; nt < 8; ++nt)
                    f2[mt][nt] = __builtin_amdgcn_mfma_f32_16x16x32_bf16(Af[mt], Bf[nt], f2[mt][nt], 0, 0, 0);
        }
#pragma unroll
        for (int mt = 0; mt < 2; ++mt) {
            const float4 s4 = *(const float4*)(bb + 32 * w + mt * 16 + quad * 4);
            const float shf[4] = {s4.x, s4.y, s4.z, s4.w};
#pragma unroll
            for (int nt = 0; nt < 8; ++nt)
#pragma unroll
                for (int r = 0; r < 4; ++r)
                    out[(size_t)(b * 256 + 32 * w + mt * 16 + quad * 4 + r) * HW_ + n0 + nt * 16 + pl]
                        = fmaxf(f2[mt][nt][r] + shf[r], 0.f);
        }
    }
}

// ---------------------------------------------------------------------------
extern "C" void kernel_launch(void* const* d_in, const int* in_sizes, int n_in,
                              void* d_out, int out_size, void* d_ws, size_t ws_size,
                              hipStream_t stream)
{
    const float* query = (const float*)d_in[0];
    const float* key   = (const float*)d_in[1];
    const float* val   = (const float*)d_in[2];
    const int*   mask  = (const int*)  d_in[3];
    const float* Wq1 = (const float*)d_in[4];  const float* sq1 = (const float*)d_in[5];  const float* bq1 = (const float*)d_in[6];
    const float* Wq2 = (const float*)d_in[7];  const float* sq2 = (const float*)d_in[8];  const float* bq2 = (const float*)d_in[9];
    const float* Wk1 = (const float*)d_in[10]; const float* sk1 = (const float*)d_in[11]; const float* bk1 = (const float*)d_in[12];
    const float* Wk2 = (const float*)d_in[13]; const float* sk2 = (const float*)d_in[14]; const float* bk2 = (const float*)d_in[15];
    const float* Wv  = (const float*)d_in[16]; const float* sv  = (const float*)d_in[17]; const float* bv  = (const float*)d_in[18];
    const float* Wo  = (const float*)d_in[19]; const float* so  = (const float*)d_in[20]; const float* bo  = (const float*)d_in[21];
    const float* Wb  = (const float*)d_in[22]; const float* sb  = (const float*)d_in[23]; const float* bb  = (const float*)d_in[24];

    char* ws = (char*)d_ws;
    bf16*   qt   = (bf16*)(ws);                        // [B][HW][C] bf16 : 16 MB
    bf16*   kbuf = (bf16*)(ws + (16u << 20));          // [B][K][C]  bf16 : 1 MB
    bf16*   vbuf = (bf16*)(ws + (17u << 20));          // [B][C][K]  bf16 : 1 MB
    char*   wbase = ws + (18u << 20);
    __bf16* Wq1p = (__bf16*)(wbase);
    __bf16* Wq2p = (__bf16*)(wbase + (32u << 10));
    __bf16* Wop  = (__bf16*)(wbase + (64u << 10));
    __bf16* Wbp  = (__bf16*)(wbase + (96u << 10));     // 128 KB
    float* outp = (float*)d_out;

    prep_kernel<<<1600, 256, 0, stream>>>(
        query, key, val,
        Wq1, sq1, Wq2, sq2, Wo, so, Wb, sb,
        Wk1, sk1, bk1, Wk2, sk2, bk2, Wv, sv, bv,
        qt, kbuf, vbuf, Wq1p, Wq2p, Wop, Wbp);
    mega_kernel<<<dim3(HW_ / 128, B_), 512, 0, stream>>>(
        qt, kbuf, vbuf, mask,
        Wq1p, bq1, Wq2p, bq2, Wop, bo, Wbp, bb, outp);
}

// Round 10
// 221.878 us; speedup vs baseline: 1.3553x; 1.3553x over previous
//
#include <hip/hip_runtime.h>
#include <hip/hip_bf16.h>

#define B_    4
#define C_    128
#define HW_   16384
#define K_    1024
// softmax runs in log2 domain: fold 128^-0.5 * log2(e) into the QK epilogue FMA
#define SC2_  0.12751734f
#define NEGL_ (-1.4427e7f)        // NEG * log2(e)
#define DTHR_ 8.0f                // defer-max threshold (log2 units): p <= 2^8

using bf16 = __hip_bfloat16;
typedef __bf16 b8v __attribute__((ext_vector_type(8)));
typedef __bf16 b4v __attribute__((ext_vector_type(4)));
typedef __bf16 b2v __attribute__((ext_vector_type(2)));
typedef float  f4v __attribute__((ext_vector_type(4)));

__device__ __forceinline__ b8v ldb8(const void* p) { return *(const b8v*)p; }
__device__ __forceinline__ b4v ldb4(const void* p) { return *(const b4v*)p; }

#define XSTRIDE 272   // 256 B row + 16 pad (b128 frag reads at bank floor)
#define KSTRIDE 272
#define VSTRIDE 136   // proven V layout: 128 B row + 8 pad, ldb4-pair reads

// xor-16 butterfly max/sum via v_permlane16_swap_b32 (VALU; replaces
// ds_bpermute ~120cyc with ~4cyc, off the LDS pipe). With a=b=x the swap
// exchanges odd 16-rows of a with even 16-rows of b, so op(a,b) = xor16.
__device__ __forceinline__ float pl16_max(float x) {
    float a = x, b = x;
    asm volatile("v_permlane16_swap_b32 %0, %1" : "+v"(a), "+v"(b));
    return fmaxf(a, b);
}
__device__ __forceinline__ float pl32_max(float x) {
    float a = x, b = x;
    asm volatile("v_permlane32_swap_b32 %0, %1" : "+v"(a), "+v"(b));
    return fmaxf(a, b);
}
__device__ __forceinline__ float pl16_add(float x) {
    float a = x, b = x;
    asm volatile("v_permlane16_swap_b32 %0, %1" : "+v"(a), "+v"(b));
    return a + b;
}
__device__ __forceinline__ float pl32_add(float x) {
    float a = x, b = x;
    asm volatile("v_permlane32_swap_b32 %0, %1" : "+v"(a), "+v"(b));
    return a + b;
}

// weight row (f32) -> bf16 fragment with BN scale folded, inline
__device__ __forceinline__ b8v ldw8(const float* wp, float sc) {
    const float4 a = *(const float4*)wp;
    const float4 c = *(const float4*)(wp + 4);
    b8v r;
    r[0] = (__bf16)(a.x * sc); r[1] = (__bf16)(a.y * sc);
    r[2] = (__bf16)(a.z * sc); r[3] = (__bf16)(a.w * sc);
    r[4] = (__bf16)(c.x * sc); r[5] = (__bf16)(c.y * sc);
    r[6] = (__bf16)(c.z * sc); r[7] = (__bf16)(c.w * sc);
    return r;
}

// ---------------------------------------------------------------------------
// prep: EXACT R7 (proven, parallel kv).
//   blk [0,64)       : K projection tile (b = blk>>4, p0 = (blk&15)*64)
//   blk [64,128)     : V projection tile
//   blk [128,1152)   : query transpose (R3-proven f32-staged pattern)
//   blk [1152,1600)  : mega weight prep (Wq1,Wq2,Wo,Wb)
// ---------------------------------------------------------------------------
__global__ __launch_bounds__(256, 4) void prep_kernel(
    const float* __restrict__ query, const float* __restrict__ key, const float* __restrict__ val,
    const float* __restrict__ Wq1, const float* __restrict__ sq1,
    const float* __restrict__ Wq2, const float* __restrict__ sq2,
    const float* __restrict__ Wo,  const float* __restrict__ so,
    const float* __restrict__ Wb,  const float* __restrict__ sb,
    const float* __restrict__ Wk1, const float* __restrict__ sk1, const float* __restrict__ bk1,
    const float* __restrict__ Wk2, const float* __restrict__ sk2, const float* __restrict__ bk2,
    const float* __restrict__ Wv,  const float* __restrict__ sv_, const float* __restrict__ bv,
    bf16* __restrict__ qt, bf16* __restrict__ kbuf, bf16* __restrict__ vbuf,
    __bf16* __restrict__ Wq1p, __bf16* __restrict__ Wq2p,
    __bf16* __restrict__ Wop,  __bf16* __restrict__ Wbp)
{
    __shared__ __align__(16) char SM[34816];
    const int blk = blockIdx.x, t = threadIdx.x;
    const int pl64 = t & 63, cg = t >> 6;

    auto scatter_tp = [&](const float* src, int L, int p0, int b, char* dst) {
#pragma unroll 4
        for (int i2 = 0; i2 < 32; ++i2) {
            const int c = cg * 32 + i2;
            const float f = src[(size_t)(b * 128 + c) * L + p0 + pl64];
            *(__bf16*)(dst + pl64 * XSTRIDE + 2 * c) = (__bf16)f;
        }
    };

    if (blk < 64) {
        // ================= K projection: one 64-position tile =================
        const int b = blk >> 4, p0 = (blk & 15) * 64;
        const int w = t >> 6, lane = t & 63;
        const int pl = lane & 15, quad = lane >> 4;
        const int ob = 32 * w;
        char* Xs = SM;
        char* Ys = SM + 17408;

        b8v W1f[2][4], W2f[2][4];
#pragma unroll
        for (int mt = 0; mt < 2; ++mt)
#pragma unroll
            for (int s = 0; s < 4; ++s) {
                const int row = ob + mt * 16 + pl;
                W1f[mt][s] = ldw8(Wk1 + row * 128 + s * 32 + quad * 8, sk1[row]);
                W2f[mt][s] = ldw8(Wk2 + row * 128 + s * 32 + quad * 8, sk2[row]);
            }

        scatter_tp(key, K_, p0, b, Xs);
        __syncthreads();

        f4v acc[2][4];
#pragma unroll
        for (int mt = 0; mt < 2; ++mt)
#pragma unroll
            for (int nt = 0; nt < 4; ++nt) acc[mt][nt] = (f4v){0.f, 0.f, 0.f, 0.f};
#pragma unroll
        for (int s = 0; s < 4; ++s) {
            b8v Bf[4];
#pragma unroll
            for (int nt = 0; nt < 4; ++nt)
                Bf[nt] = ldb8(Xs + (nt * 16 + pl) * XSTRIDE + s * 64 + quad * 16);
#pragma unroll
            for (int mt = 0; mt < 2; ++mt)
#pragma unroll
                for (int nt = 0; nt < 4; ++nt)
                    acc[mt][nt] = __builtin_amdgcn_mfma_f32_16x16x32_bf16(W1f[mt][s], Bf[nt], acc[mt][nt], 0, 0, 0);
        }
#pragma unroll
        for (int mt = 0; mt < 2; ++mt) {
            const float4 s4 = *(const float4*)(bk1 + ob + mt * 16 + quad * 4);
            const float shf[4] = {s4.x, s4.y, s4.z, s4.w};
#pragma unroll
            for (int nt = 0; nt < 4; ++nt) {
                b4v y;
#pragma unroll
                for (int r = 0; r < 4; ++r) y[r] = (__bf16)fmaxf(acc[mt][nt][r] + shf[r], 0.f);
                *(b4v*)(Ys + (nt * 16 + pl) * XSTRIDE + (ob + mt * 16 + quad * 4) * 2) = y;
            }
        }
        __syncthreads();

        f4v acc2[2][4];
#pragma unroll
        for (int mt = 0; mt < 2; ++mt)
#pragma unroll
            for (int nt = 0; nt < 4; ++nt) acc2[mt][nt] = (f4v){0.f, 0.f, 0.f, 0.f};
#pragma unroll
        for (int s = 0; s < 4; ++s) {
            b8v Bf[4];
#pragma unroll
            for (int nt = 0; nt < 4; ++nt)
                Bf[nt] = ldb8(Ys + (nt * 16 + pl) * XSTRIDE + s * 64 + quad * 16);
#pragma unroll
            for (int mt = 0; mt < 2; ++mt)
#pragma unroll
                for (int nt = 0; nt < 4; ++nt)
                    acc2[mt][nt] = __builtin_amdgcn_mfma_f32_16x16x32_bf16(W2f[mt][s], Bf[nt], acc2[mt][nt], 0, 0, 0);
        }
        bf16* kdst = kbuf + ((size_t)b * K_ + p0) * 128;
#pragma unroll
        for (int mt = 0; mt < 2; ++mt) {
            const float4 s4 = *(const float4*)(bk2 + ob + mt * 16 + quad * 4);
            const float shf[4] = {s4.x, s4.y, s4.z, s4.w};
#pragma unroll
            for (int nt = 0; nt < 4; ++nt) {
                b4v y;
#pragma unroll
                for (int r = 0; r < 4; ++r) y[r] = (__bf16)fmaxf(acc2[mt][nt][r] + shf[r], 0.f);
                *(b4v*)(kdst + (size_t)(nt * 16 + pl) * 128 + ob + mt * 16 + quad * 4) = y;
            }
        }
    } else if (blk < 128) {
        // ================= V projection: one 64-position tile =================
        const int i = blk - 64;
        const int b = i >> 4, p0 = (i & 15) * 64;
        const int w = t >> 6, lane = t & 63;
        const int pl = lane & 15, quad = lane >> 4;
        const int ob = 32 * w;
        char* Xs = SM;

        b8v Wvf[2][4];
#pragma unroll
        for (int mt = 0; mt < 2; ++mt)
#pragma unroll
            for (int s = 0; s < 4; ++s) {
                const int row = ob + mt * 16 + pl;
                Wvf[mt][s] = ldw8(Wv + row * 128 + s * 32 + quad * 8, sv_[row]);
            }

        scatter_tp(val, K_, p0, b, Xs);
        __syncthreads();

        f4v acc[2][4];
#pragma unroll
        for (int mt = 0; mt < 2; ++mt)
#pragma unroll
            for (int nt = 0; nt < 4; ++nt) acc[mt][nt] = (f4v){0.f, 0.f, 0.f, 0.f};
#pragma unroll
        for (int s = 0; s < 4; ++s) {
            b8v Bf[4];
#pragma unroll
            for (int nt = 0; nt < 4; ++nt)
                Bf[nt] = ldb8(Xs + (nt * 16 + pl) * XSTRIDE + s * 64 + quad * 16);
#pragma unroll
            for (int mt = 0; mt < 2; ++mt)
#pragma unroll
                for (int nt = 0; nt < 4; ++nt)
                    acc[mt][nt] = __builtin_amdgcn_mfma_f32_16x16x32_bf16(Wvf[mt][s], Bf[nt], acc[mt][nt], 0, 0, 0);
        }
        bf16* vdst = vbuf + (size_t)b * 128 * K_;
#pragma unroll
        for (int mt = 0; mt < 2; ++mt) {
            const float4 s4 = *(const float4*)(bv + ob + mt * 16 + quad * 4);
            const float shf[4] = {s4.x, s4.y, s4.z, s4.w};
#pragma unroll
            for (int nt = 0; nt < 4; ++nt)
#pragma unroll
                for (int r = 0; r < 4; ++r)
                    vdst[(size_t)(ob + mt * 16 + quad * 4 + r) * K_ + p0 + nt * 16 + pl]
                        = __float2bfloat16(fmaxf(acc[mt][nt][r] + shf[r], 0.f));
        }
    } else if (blk < 1152) {
        // ================= query transpose (R3-proven) =================
        float* Xs2 = (float*)SM;               // f32 [64][129] = 33024 B
        const int i = blk - 128;
        const int b = i >> 8, p0 = (i & 255) * 64;
        const int pl = t & 63, cgq = t >> 6;
#pragma unroll 4
        for (int i2 = 0; i2 < 32; ++i2) {
            const int c = cgq * 32 + i2;
            Xs2[pl * 129 + c] = query[(size_t)(b * 128 + c) * HW_ + p0 + pl];
        }
        __syncthreads();
#pragma unroll 4
        for (int it = 0; it < 16; ++it) {
            const int p = it * 4 + cgq;
            b2v pk2;
            pk2[0] = (__bf16)Xs2[p * 129 + 2 * pl];
            pk2[1] = (__bf16)Xs2[p * 129 + 2 * pl + 1];
            *(b2v*)(qt + ((size_t)b * HW_ + p0 + p) * 128 + 2 * pl) = pk2;
        }
    } else {
        // ================= mega weight prep =================
        const int idx = (blk - 1152) * 256 + t;
        if (idx < 16384)      { Wq1p[idx] = (__bf16)(Wq1[idx] * sq1[idx >> 7]); }
        else if (idx < 32768) { const int i2 = idx - 16384; Wq2p[i2] = (__bf16)(Wq2[i2] * sq2[i2 >> 7]); }
        else if (idx < 49152) { const int i2 = idx - 32768; Wop[i2]  = (__bf16)(Wo[i2]  * so[i2 >> 7]); }
        else                  { const int i2 = idx - 49152; Wbp[i2]  = (__bf16)(Wb[i2]  * sb[i2 >> 8]); }
    }
}

// ---------------------------------------------------------------------------
// mega: EXACT R8 structure (best proven: 88.6 us — dbuf K/V, 1 lgkm-barrier
// per chunk) + ONE change: softmax reduction shuffles use gfx950
// v_permlane{16,32}_swap_b32 (VALU, ~4cyc) instead of ds_bpermute (~120cyc
// serial latency on the LDS pipe) — shortens the per-chunk critical chain.
// LDS 73728 (2 blocks/CU). grid (HW/128, B), 512 threads.
// ---------------------------------------------------------------------------
__global__ __launch_bounds__(512, 4) void mega_kernel(
    const bf16* __restrict__ qt, const bf16* __restrict__ kbuf, const bf16* __restrict__ vbuf,
    const int* __restrict__ mask,
    const __bf16* __restrict__ Wq1p, const float* __restrict__ bq1,
    const __bf16* __restrict__ Wq2p, const float* __restrict__ bq2,
    const __bf16* __restrict__ Wop,  const float* __restrict__ bo,
    const __bf16* __restrict__ Wbp,  const float* __restrict__ bb,
    float* __restrict__ out)
{
    __shared__ __align__(16) char S[73728];

    const int t = threadIdx.x, w = t >> 6, lane = t & 63;
    const int pl = lane & 15, quad = lane >> 4;
    const int n0 = blockIdx.x * 128;
    const int b  = blockIdx.y;
    const int ob = 16 * w;                     // 16-channel slice per wave

    char*   RA  = S;
    __bf16* RAh = (__bf16*)S;
    __bf16* RBh = (__bf16*)(S + 34816);
    char* xl = RA + (t >> 4) * XSTRIDE + (t & 15) * 16;

    // ================= phase 1: q projection (into LDS) =================
    {
        const char* qg = (const char*)(qt + ((size_t)b * HW_ + n0) * 128) + t * 16;
#pragma unroll
        for (int i = 0; i < 4; ++i)
            *(float4*)(xl + i * 32 * XSTRIDE) = *(const float4*)(qg + i * 8192);
    }
    {
        b8v W1f[4], W2f[4];
#pragma unroll
        for (int s = 0; s < 4; ++s) {
            W1f[s] = ldb8(Wq1p + (ob + pl) * 128 + s * 32 + quad * 8);
            W2f[s] = ldb8(Wq2p + (ob + pl) * 128 + s * 32 + quad * 8);
        }
        __syncthreads();                       // sync1: q-tile in RA

        f4v a1[8];
#pragma unroll
        for (int nt = 0; nt < 8; ++nt) a1[nt] = (f4v){0.f, 0.f, 0.f, 0.f};
#pragma unroll
        for (int s = 0; s < 4; ++s) {
            b8v Bf[8];
#pragma unroll
            for (int nt = 0; nt < 8; ++nt)
                Bf[nt] = ldb8(RA + (nt * 16 + pl) * XSTRIDE + s * 64 + quad * 16);
#pragma unroll
            for (int nt = 0; nt < 8; ++nt)
                a1[nt] = __builtin_amdgcn_mfma_f32_16x16x32_bf16(W1f[s], Bf[nt], a1[nt], 0, 0, 0);
        }
        {
            const float4 s4 = *(const float4*)(bq1 + ob + quad * 4);
            const float shf[4] = {s4.x, s4.y, s4.z, s4.w};
#pragma unroll
            for (int nt = 0; nt < 8; ++nt) {
                b4v y;
#pragma unroll
                for (int r = 0; r < 4; ++r) y[r] = (__bf16)fmaxf(a1[nt][r] + shf[r], 0.f);
                *(b4v*)&RBh[(nt * 16 + pl) * 136 + ob + quad * 4] = y;
            }
        }
        __syncthreads();                       // sync2: y1 in RB, RA reads done

        f4v a2[8];
#pragma unroll
        for (int nt = 0; nt < 8; ++nt) a2[nt] = (f4v){0.f, 0.f, 0.f, 0.f};
#pragma unroll
        for (int s = 0; s < 4; ++s) {
            b8v Bf[8];
#pragma unroll
            for (int nt = 0; nt < 8; ++nt)
                Bf[nt] = *(const b8v*)&RBh[(nt * 16 + pl) * 136 + s * 32 + quad * 8];
#pragma unroll
            for (int nt = 0; nt < 8; ++nt)
                a2[nt] = __builtin_amdgcn_mfma_f32_16x16x32_bf16(W2f[s], Bf[nt], a2[nt], 0, 0, 0);
        }
        {
            const float4 s4 = *(const float4*)(bq2 + ob + quad * 4);
            const float shf[4] = {s4.x, s4.y, s4.z, s4.w};
#pragma unroll
            for (int nt = 0; nt < 8; ++nt) {
                b4v y;
#pragma unroll
                for (int r = 0; r < 4; ++r) y[r] = (__bf16)fmaxf(a2[nt][r] + shf[r], 0.f);
                *(b4v*)&RAh[(nt * 16 + pl) * 136 + ob + quad * 4] = y;
            }
        }
        __syncthreads();                       // sync3: q[pos][c] in RA
    }

    // q fragments: wave w owns queries w*16..w*16+15 (1 tile)
    b8v qf[4];
#pragma unroll
    for (int s = 0; s < 4; ++s)
        qf[s] = ldb8(RA + (w * 16 + pl) * XSTRIDE + s * 64 + quad * 16);
    __syncthreads();                           // sync4: qf read, RA free

    // ================= phase 2: attention (dbuf, 1 barrier/chunk) =========
    float* bias = (float*)S;                   // 4096 B
    char* kt0 = S + 4096;                      // 2 x 17408
    char* kt1 = S + 21504;
    char* vt0 = S + 38912;                     // 2 x 17408
    char* vt1 = S + 56320;                     // ends 73728

    const bf16* kpt = kbuf + (size_t)b * K_ * 128;
    const bf16* vpt = vbuf + (size_t)b * 128 * K_;
    const char* kg = (const char*)kpt + t * 16;
    const char* vg = (const char*)(vpt + (size_t)(t >> 3) * K_) + (t & 7) * 16;
    const int klo = (t >> 4) * KSTRIDE + (t & 15) * 16;
    const int vlo = (t >> 3) * VSTRIDE + (t & 7) * 16;

    float4 k_r0 = *(const float4*)(kg);
    float4 k_r1 = *(const float4*)(kg + 8192);
    float4 v_r0 = *(const float4*)(vg);
    float4 v_r1 = *(const float4*)(vg + 131072);

    for (int i2 = t; i2 < K_; i2 += 512)
        bias[i2] = (mask[b * K_ + i2] != 0) ? 0.f : NEGL_;

    {   // prologue: stage chunk 0 into buf0
        char* klp = kt0 + klo; char* vlp = vt0 + vlo;
        *(float4*)(klp)                = k_r0;
        *(float4*)(klp + 32 * KSTRIDE) = k_r1;
        *(float4*)(vlp)                = v_r0;
        *(float4*)(vlp + 64 * VSTRIDE) = v_r1;
    }

    f4v ac[8];
#pragma unroll
    for (int i = 0; i < 8; ++i) ac[i] = (f4v){0.f, 0.f, 0.f, 0.f};
    float mrun = -3.0e38f, lrun = 0.f;

    // lgkm-only barrier: LDS ops drained, global loads stay in flight.
#define RAW_BARRIER()                                                 \
    __builtin_amdgcn_sched_barrier(0);                                \
    asm volatile("s_waitcnt lgkmcnt(0)" ::: "memory");                \
    __builtin_amdgcn_s_barrier();                                     \
    __builtin_amdgcn_sched_barrier(0);

    RAW_BARRIER()                              // buf0 + bias visible

    for (int chunk = 0; chunk < 16; ++chunk) {
        const int cur = chunk & 1;
        const char* ktc = cur ? kt1 : kt0;
        const char* vtc = cur ? vt1 : vt0;
        char* ktn = cur ? kt0 : kt1;
        char* vtn = cur ? vt0 : vt1;
        const int k0 = chunk * 64;

        // issue next chunk's global loads now; consumed at bottom of iter
        if (chunk < 15) {
            const char* kgn = kg + (chunk + 1) * 16384;
            const char* vgn = vg + (chunk + 1) * 128;
            k_r0 = *(const float4*)(kgn);
            k_r1 = *(const float4*)(kgn + 8192);
            v_r0 = *(const float4*)(vgn);
            v_r1 = *(const float4*)(vgn + 131072);
        }

        // ---- GEMM1: log2-domain scores for this wave's 16 queries
        f4v sv[4];
        __builtin_amdgcn_s_setprio(1);
#pragma unroll
        for (int kt = 0; kt < 4; ++kt) {
            f4v a = (f4v){0.f, 0.f, 0.f, 0.f};
            const char* krow = ktc + (kt * 16 + pl) * KSTRIDE + quad * 16;
#pragma unroll
            for (int s = 0; s < 4; ++s)
                a = __builtin_amdgcn_mfma_f32_16x16x32_bf16(ldb8(krow + s * 64), qf[s], a, 0, 0, 0);
            const float4 b4 = *(const float4*)&bias[k0 + kt * 16 + quad * 4];
            const float bb4[4] = {b4.x, b4.y, b4.z, b4.w};
#pragma unroll
            for (int r = 0; r < 4; ++r) sv[kt][r] = a[r] * SC2_ + bb4[r];
        }
        __builtin_amdgcn_s_setprio(0);

        // ---- online softmax (deferred rescale T13; permlane reduces T12)
        float ml = sv[0][0];
#pragma unroll
        for (int kt = 0; kt < 4; ++kt)
#pragma unroll
            for (int r = 0; r < 4; ++r) ml = fmaxf(ml, sv[kt][r]);
        ml = pl16_max(ml);
        ml = pl32_max(ml);

        if (__any(ml > mrun + DTHR_)) {
            const float mn = fmaxf(mrun, ml);
            const float al = exp2f(mrun - mn);
            lrun *= al; mrun = mn;
            float ar[4];
#pragma unroll
            for (int r = 0; r < 4; ++r) ar[r] = __shfl(al, quad * 4 + r, 64);
#pragma unroll
            for (int ct = 0; ct < 8; ++ct)
#pragma unroll
                for (int r = 0; r < 4; ++r) ac[ct][r] *= ar[r];
        }

        b4v pk[4];
        float rs = 0.f;
#pragma unroll
        for (int kt = 0; kt < 4; ++kt)
#pragma unroll
            for (int r = 0; r < 4; ++r) {
                const float p = exp2f(sv[kt][r] - mrun); rs += p; pk[kt][r] = (__bf16)p;
            }
        rs = pl16_add(rs);
        rs = pl32_add(rs);
        lrun += rs;

        // ---- GEMM2
        const b8v A0 = __builtin_shufflevector(pk[0], pk[1], 0, 1, 2, 3, 4, 5, 6, 7);
        const b8v A1 = __builtin_shufflevector(pk[2], pk[3], 0, 1, 2, 3, 4, 5, 6, 7);
        __builtin_amdgcn_s_setprio(1);
#pragma unroll
        for (int ct = 0; ct < 8; ++ct) {
            const char* vrow = vtc + (ct * 16 + pl) * VSTRIDE + quad * 8;
            const b8v B0 = __builtin_shufflevector(ldb4(vrow),      ldb4(vrow + 32), 0, 1, 2, 3, 4, 5, 6, 7);
            const b8v B1 = __builtin_shufflevector(ldb4(vrow + 64), ldb4(vrow + 96), 0, 1, 2, 3, 4, 5, 6, 7);
            ac[ct] = __builtin_amdgcn_mfma_f32_16x16x32_bf16(A0, B0, ac[ct], 0, 0, 0);
            ac[ct] = __builtin_amdgcn_mfma_f32_16x16x32_bf16(A1, B1, ac[ct], 0, 0, 0);
        }
        __builtin_amdgcn_s_setprio(0);

        // ---- stage next chunk into the other buffer (disjoint from reads)
        if (chunk < 15) {
            char* klp = ktn + klo; char* vlp = vtn + vlo;
            *(float4*)(klp)                = k_r0;
            *(float4*)(klp + 32 * KSTRIDE) = k_r1;
            *(float4*)(vlp)                = v_r0;
            *(float4*)(vlp + 64 * VSTRIDE) = v_r1;
        }

        RAW_BARRIER()                          // reads+writes drained; swap
    }
#undef RAW_BARRIER

    // ---- epilogue: normalized ctx -> RA [pos][c] bf16
    {
        float inv[4];
#pragma unroll
        for (int r = 0; r < 4; ++r) inv[r] = 1.f / __shfl(lrun, quad * 4 + r, 64);
#pragma unroll
        for (int ct = 0; ct < 8; ++ct)
#pragma unroll
            for (int r = 0; r < 4; ++r)
                RAh[(w * 16 + quad * 4 + r) * 136 + ct * 16 + pl] = (__bf16)(ac[ct][r] * inv[r]);
    }
    __syncthreads();                           // sync5: ctx in RA

    // ================= phase 3: final =================
    b8v Wof[4];
#pragma unroll
    for (int s = 0; s < 4; ++s)
        Wof[s] = ldb8(Wop + (ob + pl) * 128 + s * 32 + quad * 8);

    const char* qg2 = (const char*)(qt + ((size_t)b * HW_ + n0) * 128) + t * 16;
    float4 q_s0 = *(const float4*)(qg2);
    float4 q_s1 = *(const float4*)(qg2 + 8192);
    float4 q_s2 = *(const float4*)(qg2 + 16384);
    float4 q_s3 = *(const float4*)(qg2 + 24576);

    {
        f4v f1[8];
#pragma unroll
        for (int nt = 0; nt < 8; ++nt) f1[nt] = (f4v){0.f, 0.f, 0.f, 0.f};
#pragma unroll
        for (int s = 0; s < 4; ++s) {
            b8v Bf[8];
#pragma unroll
            for (int nt = 0; nt < 8; ++nt)
                Bf[nt] = ldb8(RA + (nt * 16 + pl) * XSTRIDE + s * 64 + quad * 16);
#pragma unroll
            for (int nt = 0; nt < 8; ++nt)
                f1[nt] = __builtin_amdgcn_mfma_f32_16x16x32_bf16(Wof[s], Bf[nt], f1[nt], 0, 0, 0);
        }
        {
            const float4 s4 = *(const float4*)(bo + ob + quad * 4);
            const float shf[4] = {s4.x, s4.y, s4.z, s4.w};
#pragma unroll
            for (int nt = 0; nt < 8; ++nt) {
                b4v y;
#pragma unroll
                for (int r = 0; r < 4; ++r) y[r] = (__bf16)fmaxf(f1[nt][r] + shf[r], 0.f);
                *(b4v*)&RBh[(nt * 16 + pl) * 136 + ob + quad * 4] = y;
            }
        }
    }
    __syncthreads();                           // sync6: ctx2 in RB, RA reads done

    *(float4*)(xl)                 = q_s0;
    *(float4*)(xl + 32 * XSTRIDE)  = q_s1;
    *(float4*)(xl + 64 * XSTRIDE)  = q_s2;
    *(float4*)(xl + 96 * XSTRIDE)  = q_s3;
    __syncthreads();                           // sync7: qt in RA

    {
        f4v f2[2][8];
#pragma unroll
        for (int mt = 0; mt < 2; ++mt)
#pragma unroll
            for (int nt = 0; nt < 8; ++nt) f2[mt][nt] = (f4v){0.f, 0.f, 0.f, 0.f};
#pragma unroll
        for (int ks = 0; ks < 8; ++ks) {
            b8v Af[2];
#pragma unroll
            for (int mt = 0; mt < 2; ++mt)
                Af[mt] = ldb8(Wbp + (size_t)(32 * w + mt * 16 + pl) * 256 + ks * 32 + quad * 8);
            b8v Bf[8];
            if (ks < 4) {
#pragma unroll
                for (int nt = 0; nt < 8; ++nt)
                    Bf[nt] = *(const b8v*)&RBh[(nt * 16 + pl) * 136 + ks * 32 + quad * 8];
            } else {
#pragma unroll
                for (int nt = 0; nt < 8; ++nt)
                    Bf[nt] = ldb8(RA + (nt * 16 + pl) * XSTRIDE + (ks - 4) * 64 + quad * 16);
            }
#pragma unroll
            for (int mt = 0; mt < 2; ++mt)
#pragma unroll
                for (int nt = 0; nt < 8; ++nt)
                    f2[mt][nt] = __builtin_amdgcn_mfma_f32_16x16x32_bf16(Af[mt], Bf[nt], f2[mt][nt], 0, 0, 0);
        }
#pragma unroll
        for (int mt = 0; mt < 2; ++mt) {
            const float4 s4 = *(const float4*)(bb + 32 * w + mt * 16 + quad * 4);
            const float shf[4] = {s4.x, s4.y, s4.z, s4.w};
#pragma unroll
            for (int nt = 0; nt < 8; ++nt)
#pragma unroll
                for (int r = 0; r < 4; ++r)
                    out[(size_t)(b * 256 + 32 * w + mt * 16 + quad * 4 + r) * HW_ + n0 + nt * 16 + pl]
                        = fmaxf(f2[mt][nt][r] + shf[r], 0.f);
        }
    }
}

// ---------------------------------------------------------------------------
extern "C" void kernel_launch(void* const* d_in, const int* in_sizes, int n_in,
                              void* d_out, int out_size, void* d_ws, size_t ws_size,
                              hipStream_t stream)
{
    const float* query = (const float*)d_in[0];
    const float* key   = (const float*)d_in[1];
    const float* val   = (const float*)d_in[2];
    const int*   mask  = (const int*)  d_in[3];
    const float* Wq1 = (const float*)d_in[4];  const float* sq1 = (const float*)d_in[5];  const float* bq1 = (const float*)d_in[6];
    const float* Wq2 = (const float*)d_in[7];  const float* sq2 = (const float*)d_in[8];  const float* bq2 = (const float*)d_in[9];
    const float* Wk1 = (const float*)d_in[10]; const float* sk1 = (const float*)d_in[11]; const float* bk1 = (const float*)d_in[12];
    const float* Wk2 = (const float*)d_in[13]; const float* sk2 = (const float*)d_in[14]; const float* bk2 = (const float*)d_in[15];
    const float* Wv  = (const float*)d_in[16]; const float* sv  = (const float*)d_in[17]; const float* bv  = (const float*)d_in[18];
    const float* Wo  = (const float*)d_in[19]; const float* so  = (const float*)d_in[20]; const float* bo  = (const float*)d_in[21];
    const float* Wb  = (const float*)d_in[22]; const float* sb  = (const float*)d_in[23]; const float* bb  = (const float*)d_in[24];

    char* ws = (char*)d_ws;
    bf16*   qt   = (bf16*)(ws);                        // [B][HW][C] bf16 : 16 MB
    bf16*   kbuf = (bf16*)(ws + (16u << 20));          // [B][K][C]  bf16 : 1 MB
    bf16*   vbuf = (bf16*)(ws + (17u << 20));          // [B][C][K]  bf16 : 1 MB
    char*   wbase = ws + (18u << 20);
    __bf16* Wq1p = (__bf16*)(wbase);
    __bf16* Wq2p = (__bf16*)(wbase + (32u << 10));
    __bf16* Wop  = (__bf16*)(wbase + (64u << 10));
    __bf16* Wbp  = (__bf16*)(wbase + (96u << 10));     // 128 KB
    float* outp = (float*)d_out;

    prep_kernel<<<1600, 256, 0, stream>>>(
        query, key, val,
        Wq1, sq1, Wq2, sq2, Wo, so, Wb, sb,
        Wk1, sk1, bk1, Wk2, sk2, bk2, Wv, sv, bv,
        qt, kbuf, vbuf, Wq1p, Wq2p, Wop, Wbp);
    mega_kernel<<<dim3(HW_ / 128, B_), 512, 0, stream>>>(
        qt, kbuf, vbuf, mask,
        Wq1p, bq1, Wq2p, bq2, Wop, bo, Wbp, bb, outp);
}